// Round 1
// baseline (2452.154 us; speedup 1.0000x reference)
//
#include <hip/hip_runtime.h>
#include <hip/hip_bf16.h>
#include <math.h>

// Problem constants
#define NNODE 17
#define HF    128      // GCN hidden
#define TT    128      // time steps
#define BB    256      // batch
#define LHID  256      // LSTM hidden
#define G4    1024     // 4*LHID

// ws layout in floats
#define OFF_AHAT   0                        // 289 (pad 512)
#define OFF_WT     512                      // 256*1024
#define OFF_BIAS   (OFF_WT + 262144)        // 1024
#define OFF_WIT    (OFF_BIAS + 1024)        // 128*1024
#define OFF_POOLED (OFF_WIT + 131072)       // 32768*128
#define OFF_XW     (OFF_POOLED + 4194304)   // 32768*1024
#define OFF_FEAT   (OFF_XW + 33554432)      // 256*256
// total = 38,209,024 floats = ~153 MB

// ---------------- prep: A_hat from hard-coded edge list ----------------
__global__ __launch_bounds__(64) void prep_ahat_k(float* __restrict__ Ahat) {
    __shared__ float A[289];
    __shared__ float dinv[NNODE];
    const int t = threadIdx.x;
    for (int i = t; i < 289; i += 64) A[i] = 0.f;
    __syncthreads();
    if (t == 0) {
        const int es[17] = {0,0,1,2,1,5,7,6,8,5,5,6,11,11,13,12,14};
        const int et[17] = {5,6,2,4,3,7,9,8,10,6,11,12,12,13,15,14,16};
        for (int e = 0; e < 17; e++) A[et[e]*17 + es[e]] = 1.f;
        for (int n = 0; n < NNODE; n++) A[n*17 + n] += 1.f;
    }
    __syncthreads();
    if (t < NNODE) {
        float s = 0.f;
        for (int m = 0; m < NNODE; m++) s += A[t*17 + m];
        dinv[t] = rsqrtf(s);
    }
    __syncthreads();
    for (int i = t; i < 289; i += 64) {
        int n = i / 17, m = i % 17;
        Ahat[i] = dinv[n] * A[i] * dinv[m];
    }
}

// ---------------- prep: transposes + bias sum ----------------
__global__ __launch_bounds__(256) void prep_wt_k(
    const float* __restrict__ Whh, const float* __restrict__ Wih,
    const float* __restrict__ bih, const float* __restrict__ bhh,
    float* __restrict__ WT, float* __restrict__ WIT, float* __restrict__ bias_sum)
{
    const int k = blockIdx.x;       // 0..255
    const int g0 = threadIdx.x;
    for (int g = g0; g < G4; g += 256)
        WT[(size_t)k*G4 + g] = Whh[(size_t)g*LHID + k];
    if (k < HF)
        for (int g = g0; g < G4; g += 256)
            WIT[(size_t)k*G4 + g] = Wih[(size_t)g*HF + k];
    if (k == 0)
        for (int g = g0; g < G4; g += 256)
            bias_sum[g] = bih[g] + bhh[g];
}

// ---------------- GCN two layers + mean pool, one block per frame ----------------
__global__ __launch_bounds__(128) void gcn_pool_k(
    const float* __restrict__ kp, const float* __restrict__ W1,
    const float* __restrict__ b1, const float* __restrict__ W2,
    const float* __restrict__ b2, const float* __restrict__ Ahat,
    float* __restrict__ pooled)
{
    const int f = blockIdx.x;       // frame = b*T + t
    const int j = threadIdx.x;      // feature 0..127
    __shared__ float Ah[289];
    __shared__ float X[34];
    __shared__ float AhT[128][20];  // [feature k][node n], row stride 20 keeps 16B align
    if (j < 34) X[j] = kp[(size_t)f*34 + j];
    for (int i = j; i < 289; i += 128) Ah[i] = Ahat[i];
    __syncthreads();
    // AX (17x2), redundant per thread (tiny)
    float ax0[NNODE], ax1[NNODE];
    #pragma unroll
    for (int n = 0; n < NNODE; n++) {
        float s0 = 0.f, s1 = 0.f;
        #pragma unroll
        for (int m = 0; m < NNODE; m++) {
            float a = Ah[n*17 + m];
            s0 += a * X[2*m];
            s1 += a * X[2*m + 1];
        }
        ax0[n] = s0; ax1[n] = s1;
    }
    // h1 = relu((AX) W1 + b1), column j
    const float w10 = W1[j], w11 = W1[HF + j], bb1 = b1[j];
    float h1[NNODE];
    #pragma unroll
    for (int n = 0; n < NNODE; n++)
        h1[n] = fmaxf(fmaf(ax0[n], w10, fmaf(ax1[n], w11, bb1)), 0.f);
    // g = A h1 (column j stays in-thread)
    float gcol[NNODE];
    #pragma unroll
    for (int n = 0; n < NNODE; n++) {
        float s = 0.f;
        #pragma unroll
        for (int m = 0; m < NNODE; m++) s += Ah[n*17 + m] * h1[m];
        gcol[n] = s;
    }
    #pragma unroll
    for (int n = 0; n < NNODE; n++) AhT[j][n] = gcol[n];
    __syncthreads();
    // h2pre[n][j] = sum_k AhT[k][n] * W2[k][j]
    float acc[NNODE];
    #pragma unroll
    for (int n = 0; n < NNODE; n++) acc[n] = 0.f;
    for (int k = 0; k < HF; k++) {
        float w = W2[k*HF + j];
        #pragma unroll
        for (int n = 0; n < NNODE; n++) acc[n] = fmaf(AhT[k][n], w, acc[n]);
    }
    const float bb2 = b2[j];
    float s = 0.f;
    #pragma unroll
    for (int n = 0; n < NNODE; n++) s += fmaxf(acc[n] + bb2, 0.f);
    pooled[(size_t)f*HF + j] = s * (1.f/17.f);
}

// ---------------- xw = pooled @ W_ih^T + (b_ih+b_hh) ----------------
__global__ __launch_bounds__(256) void xw_gemm_k(
    const float* __restrict__ pooled, const float* __restrict__ WIT,
    const float* __restrict__ bias_sum, float* __restrict__ xw)
{
    const int row0 = blockIdx.x * 16;
    const int col  = blockIdx.y * 256 + threadIdx.x;
    __shared__ float P[16][HF];
    #pragma unroll
    for (int i = 0; i < 8; i++) {
        int e = threadIdx.x + i*256;
        P[e >> 7][e & 127] = pooled[(size_t)(row0 + (e >> 7))*HF + (e & 127)];
    }
    __syncthreads();
    float acc[16];
    #pragma unroll
    for (int r = 0; r < 16; r++) acc[r] = 0.f;
    for (int k = 0; k < HF; k++) {
        float w = WIT[(size_t)k*G4 + col];
        #pragma unroll
        for (int r = 0; r < 16; r++) acc[r] = fmaf(P[r][k], w, acc[r]);
    }
    float bs = bias_sum[col];
    #pragma unroll
    for (int r = 0; r < 16; r++)
        xw[(size_t)(row0 + r)*G4 + col] = acc[r] + bs;
}

// ---------------- LSTM recurrence + max-over-time, 4 batch per block ----------------
__global__ __launch_bounds__(256) void lstm_k(
    const float* __restrict__ xw, const float* __restrict__ WT,
    float* __restrict__ feat)
{
    const int b0  = blockIdx.x * 4;
    const int tid = threadIdx.x;
    __shared__ float hb[2][LHID][4];   // [buf][k][batch j]
    __shared__ float zl[4][G4];        // gate exchange
    float c[4]  = {0.f, 0.f, 0.f, 0.f};
    float hm[4] = {-1e30f, -1e30f, -1e30f, -1e30f};
    *((float4*)&hb[0][tid][0]) = make_float4(0.f, 0.f, 0.f, 0.f);
    __syncthreads();
    int buf = 0;
    for (int t = 0; t < TT; t++) {
        // z accumulators: gate cols 4*tid..4*tid+3, batches j=0..3
        float4 za[4];
        #pragma unroll
        for (int jj = 0; jj < 4; jj++)
            za[jj] = *((const float4*)(xw + ((size_t)(b0 + jj)*TT + t)*G4 + 4*tid));
        #pragma unroll 4
        for (int k = 0; k < LHID; k++) {
            float4 w  = *((const float4*)(WT + (size_t)k*G4 + 4*tid));
            float4 h4 = *((const float4*)&hb[buf][k][0]);
            float hj[4] = {h4.x, h4.y, h4.z, h4.w};
            #pragma unroll
            for (int jj = 0; jj < 4; jj++) {
                za[jj].x = fmaf(hj[jj], w.x, za[jj].x);
                za[jj].y = fmaf(hj[jj], w.y, za[jj].y);
                za[jj].z = fmaf(hj[jj], w.z, za[jj].z);
                za[jj].w = fmaf(hj[jj], w.w, za[jj].w);
            }
        }
        #pragma unroll
        for (int jj = 0; jj < 4; jj++)
            *((float4*)&zl[jj][4*tid]) = za[jj];
        __syncthreads();
        // regather: unit = tid, gates i/f/g/o at tid, 256+tid, 512+tid, 768+tid
        #pragma unroll
        for (int jj = 0; jj < 4; jj++) {
            float zi = zl[jj][tid];
            float zf = zl[jj][LHID + tid];
            float zg = zl[jj][2*LHID + tid];
            float zo = zl[jj][3*LHID + tid];
            float ii = 1.f / (1.f + __expf(-zi));
            float ff = 1.f / (1.f + __expf(-zf));
            float eg = __expf(2.f*zg);  float gg = 1.f - 2.f/(eg + 1.f);
            float oo = 1.f / (1.f + __expf(-zo));
            float cn = fmaf(ff, c[jj], ii*gg);
            c[jj] = cn;
            float ec = __expf(2.f*cn);  float th = 1.f - 2.f/(ec + 1.f);
            float hh = oo * th;
            hm[jj] = fmaxf(hm[jj], hh);
            hb[buf ^ 1][tid][jj] = hh;
        }
        __syncthreads();
        buf ^= 1;
    }
    #pragma unroll
    for (int jj = 0; jj < 4; jj++)
        feat[(size_t)(b0 + jj)*LHID + tid] = hm[jj];
}

// ---------------- final FC + sigmoid ----------------
__global__ __launch_bounds__(64) void final_k(
    const float* __restrict__ feat, const float* __restrict__ Wfc,
    const float* __restrict__ bfc, float* __restrict__ out)
{
    const int b = blockIdx.x * 64 + threadIdx.x;
    float s = bfc[0];
    for (int u = 0; u < LHID; u++)
        s = fmaf(feat[(size_t)b*LHID + u], Wfc[u], s);
    out[b] = 1.f / (1.f + __expf(-s));
}

extern "C" void kernel_launch(void* const* d_in, const int* in_sizes, int n_in,
                              void* d_out, int out_size, void* d_ws, size_t ws_size,
                              hipStream_t stream) {
    const float* kp  = (const float*)d_in[0];
    const float* W1  = (const float*)d_in[1];
    const float* b1  = (const float*)d_in[2];
    const float* W2  = (const float*)d_in[3];
    const float* b2  = (const float*)d_in[4];
    const float* Wih = (const float*)d_in[5];
    const float* Whh = (const float*)d_in[6];
    const float* bih = (const float*)d_in[7];
    const float* bhh = (const float*)d_in[8];
    const float* Wfc = (const float*)d_in[9];
    const float* bfc = (const float*)d_in[10];

    float* ws     = (float*)d_ws;
    float* Ahat   = ws + OFF_AHAT;
    float* WT     = ws + OFF_WT;
    float* bias   = ws + OFF_BIAS;
    float* WIT    = ws + OFF_WIT;
    float* pooled = ws + OFF_POOLED;
    float* xw     = ws + OFF_XW;
    float* feat   = ws + OFF_FEAT;
    float* out    = (float*)d_out;

    hipLaunchKernelGGL(prep_ahat_k, dim3(1), dim3(64), 0, stream, Ahat);
    hipLaunchKernelGGL(prep_wt_k, dim3(256), dim3(256), 0, stream,
                       Whh, Wih, bih, bhh, WT, WIT, bias);
    hipLaunchKernelGGL(gcn_pool_k, dim3(BB*TT), dim3(128), 0, stream,
                       kp, W1, b1, W2, b2, Ahat, pooled);
    hipLaunchKernelGGL(xw_gemm_k, dim3(BB*TT/16, 4), dim3(256), 0, stream,
                       pooled, WIT, bias, xw);
    hipLaunchKernelGGL(lstm_k, dim3(BB/4), dim3(256), 0, stream, xw, WT, feat);
    hipLaunchKernelGGL(final_k, dim3(4), dim3(64), 0, stream, feat, Wfc, bfc, out);
}

// Round 4
// 1501.401 us; speedup vs baseline: 1.6332x; 1.6332x over previous
//
#include <hip/hip_runtime.h>
#include <hip/hip_bf16.h>
#include <math.h>

// Problem constants
#define NNODE 17
#define HF    128      // GCN hidden
#define TT    128      // time steps
#define BB    256      // batch
#define LHID  256      // LSTM hidden
#define G4    1024     // 4*LHID

typedef short short8 __attribute__((ext_vector_type(8)));
typedef float f32x4  __attribute__((ext_vector_type(4)));

// ws layout in floats
#define OFF_AHAT   0                         // 289 (pad 512)
#define OFF_WIT    512                       // 128*1024
#define OFF_BIAS   (OFF_WIT + 131072)        // 1024
#define OFF_WPK    (OFF_BIAS + 1024)         // 262144 ushort = 131072 floats (bf16-packed Whh)
#define OFF_POOLED (OFF_WPK + 131072)        // 32768*128
#define OFF_XW     (OFF_POOLED + 4194304)    // 32768*1024
#define OFF_FEAT   (OFF_XW + 33554432)       // 256*256
// total = 38,077,952 floats ~= 152 MB

__device__ inline unsigned int f2bf(float x) {   // fp32 -> bf16 bits, RNE
    unsigned int u = __float_as_uint(x);
    return (u + 0x7fffu + ((u >> 16) & 1u)) >> 16;
}

// ---------------- prep: A_hat from hard-coded edge list ----------------
__global__ __launch_bounds__(64) void prep_ahat_k(float* __restrict__ Ahat) {
    __shared__ float A[289];
    __shared__ float dinv[NNODE];
    const int t = threadIdx.x;
    for (int i = t; i < 289; i += 64) A[i] = 0.f;
    __syncthreads();
    if (t == 0) {
        const int es[17] = {0,0,1,2,1,5,7,6,8,5,5,6,11,11,13,12,14};
        const int et[17] = {5,6,2,4,3,7,9,8,10,6,11,12,12,13,15,14,16};
        for (int e = 0; e < 17; e++) A[et[e]*17 + es[e]] = 1.f;
        for (int n = 0; n < NNODE; n++) A[n*17 + n] += 1.f;
    }
    __syncthreads();
    if (t < NNODE) {
        float s = 0.f;
        for (int m = 0; m < NNODE; m++) s += A[t*17 + m];
        dinv[t] = rsqrtf(s);
    }
    __syncthreads();
    for (int i = t; i < 289; i += 64) {
        int n = i / 17, m = i % 17;
        Ahat[i] = dinv[n] * A[i] * dinv[m];
    }
}

// ---------------- prep: W_ih transpose + bias sum ----------------
__global__ __launch_bounds__(256) void prep_wt_k(
    const float* __restrict__ Wih,
    const float* __restrict__ bih, const float* __restrict__ bhh,
    float* __restrict__ WIT, float* __restrict__ bias_sum)
{
    const int k = blockIdx.x;       // 0..127
    const int g0 = threadIdx.x;
    for (int g = g0; g < G4; g += 256)
        WIT[(size_t)k*G4 + g] = Wih[(size_t)g*HF + k];
    if (k == 0)
        for (int g = g0; g < G4; g += 256)
            bias_sum[g] = bih[g] + bhh[g];
}

// ---------------- prep: pack Whh into bf16 MFMA B-fragment order ----------------
// B frag for mfma_f32_16x16x32_bf16: lane l supplies B[k][col], col = l&15,
// k = kc*32 + (l>>4)*8 + j (j=0..7). Packed layout:
// Wpk[ ((w*8 + t)*8 + kc)*512 + lane*8 + j ],  col = w*128 + t*16 + (lane&15)
__global__ __launch_bounds__(256) void prep_pack_k(
    const float* __restrict__ Whh, unsigned short* __restrict__ Wpk)
{
    const int tid = blockIdx.x * 256 + threadIdx.x;   // 0..32767
    const int lane = tid & 63;
    const int kc   = (tid >> 6) & 7;
    const int t    = (tid >> 9) & 7;
    const int w    = (tid >> 12) & 7;
    const int col  = w*128 + t*16 + (lane & 15);
    const int kb   = kc*32 + (lane >> 4)*8;
    const float4 v0 = *(const float4*)(Whh + (size_t)col*LHID + kb);
    const float4 v1 = *(const float4*)(Whh + (size_t)col*LHID + kb + 4);
    uint4 o;
    o.x = f2bf(v0.x) | (f2bf(v0.y) << 16);
    o.y = f2bf(v0.z) | (f2bf(v0.w) << 16);
    o.z = f2bf(v1.x) | (f2bf(v1.y) << 16);
    o.w = f2bf(v1.z) | (f2bf(v1.w) << 16);
    *(uint4*)(Wpk + (size_t)tid*8) = o;
}

// ---------------- GCN two layers + mean pool, one block per frame ----------------
__global__ __launch_bounds__(128) void gcn_pool_k(
    const float* __restrict__ kp, const float* __restrict__ W1,
    const float* __restrict__ b1, const float* __restrict__ W2,
    const float* __restrict__ b2, const float* __restrict__ Ahat,
    float* __restrict__ pooled)
{
    const int f = blockIdx.x;       // frame = b*T + t
    const int j = threadIdx.x;      // feature 0..127
    __shared__ float Ah[289];
    __shared__ float X[34];
    __shared__ float AhT[128][20];
    if (j < 34) X[j] = kp[(size_t)f*34 + j];
    for (int i = j; i < 289; i += 128) Ah[i] = Ahat[i];
    __syncthreads();
    float ax0[NNODE], ax1[NNODE];
    #pragma unroll
    for (int n = 0; n < NNODE; n++) {
        float s0 = 0.f, s1 = 0.f;
        #pragma unroll
        for (int m = 0; m < NNODE; m++) {
            float a = Ah[n*17 + m];
            s0 += a * X[2*m];
            s1 += a * X[2*m + 1];
        }
        ax0[n] = s0; ax1[n] = s1;
    }
    const float w10 = W1[j], w11 = W1[HF + j], bb1 = b1[j];
    float h1[NNODE];
    #pragma unroll
    for (int n = 0; n < NNODE; n++)
        h1[n] = fmaxf(fmaf(ax0[n], w10, fmaf(ax1[n], w11, bb1)), 0.f);
    float gcol[NNODE];
    #pragma unroll
    for (int n = 0; n < NNODE; n++) {
        float s = 0.f;
        #pragma unroll
        for (int m = 0; m < NNODE; m++) s += Ah[n*17 + m] * h1[m];
        gcol[n] = s;
    }
    #pragma unroll
    for (int n = 0; n < NNODE; n++) AhT[j][n] = gcol[n];
    __syncthreads();
    float acc[NNODE];
    #pragma unroll
    for (int n = 0; n < NNODE; n++) acc[n] = 0.f;
    for (int k = 0; k < HF; k++) {
        float w = W2[k*HF + j];
        #pragma unroll
        for (int n = 0; n < NNODE; n++) acc[n] = fmaf(AhT[k][n], w, acc[n]);
    }
    const float bb2 = b2[j];
    float s = 0.f;
    #pragma unroll
    for (int n = 0; n < NNODE; n++) s += fmaxf(acc[n] + bb2, 0.f);
    pooled[(size_t)f*HF + j] = s * (1.f/17.f);
}

// ---------------- xw = pooled @ W_ih^T + (b_ih+b_hh) ----------------
__global__ __launch_bounds__(256) void xw_gemm_k(
    const float* __restrict__ pooled, const float* __restrict__ WIT,
    const float* __restrict__ bias_sum, float* __restrict__ xw)
{
    const int row0 = blockIdx.x * 16;
    const int col  = blockIdx.y * 256 + threadIdx.x;
    __shared__ float P[16][HF];
    #pragma unroll
    for (int i = 0; i < 8; i++) {
        int e = threadIdx.x + i*256;
        P[e >> 7][e & 127] = pooled[(size_t)(row0 + (e >> 7))*HF + (e & 127)];
    }
    __syncthreads();
    float acc[16];
    #pragma unroll
    for (int r = 0; r < 16; r++) acc[r] = 0.f;
    for (int k = 0; k < HF; k++) {
        float w = WIT[(size_t)k*G4 + col];
        #pragma unroll
        for (int r = 0; r < 16; r++) acc[r] = fmaf(P[r][k], w, acc[r]);
    }
    float bs = bias_sum[col];
    #pragma unroll
    for (int r = 0; r < 16; r++)
        xw[(size_t)(row0 + r)*G4 + col] = acc[r] + bs;
}

// ---------------- MFMA LSTM: 8 batches/block, 32 blocks, 512 threads ----------------
// Per step: z[16(pad8),1024] = hpack(bf16) @ Wpk(bf16) via mfma_f32_16x16x32_bf16,
// z exchange through LDS, elementwise gates fp32, h repacked to bf16 A-frag layout.
__global__ __launch_bounds__(512, 2) void lstm_mfma_k(
    const float* __restrict__ xw, const unsigned short* __restrict__ Wpk,
    float* __restrict__ feat)
{
    const int b0  = blockIdx.x * 8;
    const int tid = threadIdx.x;
    const int w   = tid >> 6;          // wave id = epilogue row
    const int l   = tid & 63;
    const int eu0 = (tid & 63) << 2;   // epilogue unit base (4 units/thread)

    __shared__ float zbuf[8][G4];                 // 32 KB
    __shared__ unsigned short hpack[8][64][8];    // 8 KB, A-frag order

    // zero h (t=0 state); rows 8..15 of the padded M stay zero forever
    ((uint4*)hpack)[tid] = make_uint4(0u, 0u, 0u, 0u);

    float c[4]  = {0.f, 0.f, 0.f, 0.f};
    float hm[4] = {-1e30f, -1e30f, -1e30f, -1e30f};
    const unsigned short* wbase = Wpk + (size_t)w*32768 + l*8;
    const float* xwrow = xw + ((size_t)(b0 + w)*TT)*G4 + eu0;
    __syncthreads();

    for (int t = 0; t < TT; ++t) {
        // prefetch xw for this step's epilogue (latency hidden under MFMA phase)
        float4 xg[4];
        #pragma unroll
        for (int g = 0; g < 4; ++g)
            xg[g] = *(const float4*)(xwrow + (size_t)t*G4 + g*256);

        // A fragments: h for all 8 k-chunks (reused across all 8 col-tiles)
        short8 a[8];
        #pragma unroll
        for (int kc = 0; kc < 8; ++kc)
            a[kc] = *(const short8*)&hpack[kc][l][0];

        // MFMA phase: wave w covers gate cols [128w, 128w+128), double-buffered B
        short8 bcur[8], bnext[8];
        #pragma unroll
        for (int kc = 0; kc < 8; ++kc)
            bcur[kc] = *(const short8*)(wbase + kc*512);
        for (int tt = 0; tt < 8; ++tt) {
            if (tt < 7) {
                #pragma unroll
                for (int kc = 0; kc < 8; ++kc)
                    bnext[kc] = *(const short8*)(wbase + (tt+1)*4096 + kc*512);
            }
            f32x4 acc = {0.f, 0.f, 0.f, 0.f};
            #pragma unroll
            for (int kc = 0; kc < 8; ++kc)
                acc = __builtin_amdgcn_mfma_f32_16x16x32_bf16(a[kc], bcur[kc], acc, 0, 0, 0);
            // C/D layout: col = lane&15, row = (lane>>4)*4 + reg  [m89-verified]
            if (l < 32) {
                const int zr = (l >> 4) * 4;
                const int zc = w*128 + tt*16 + (l & 15);
                #pragma unroll
                for (int r = 0; r < 4; ++r) zbuf[zr + r][zc] = acc[r];
            }
            #pragma unroll
            for (int kc = 0; kc < 8; ++kc) bcur[kc] = bnext[kc];
        }
        __syncthreads();

        // epilogue: 4 cells per thread (row = w, units eu0..eu0+3)
        float4 zi = *(const float4*)&zbuf[w][0*256 + eu0];
        float4 zf = *(const float4*)&zbuf[w][1*256 + eu0];
        float4 zg = *(const float4*)&zbuf[w][2*256 + eu0];
        float4 zo = *(const float4*)&zbuf[w][3*256 + eu0];
        float hval[4];
        #pragma unroll
        for (int q = 0; q < 4; ++q) {
            float vi = ((const float*)&zi)[q] + ((const float*)&xg[0])[q];
            float vf = ((const float*)&zf)[q] + ((const float*)&xg[1])[q];
            float vg = ((const float*)&zg)[q] + ((const float*)&xg[2])[q];
            float vo = ((const float*)&zo)[q] + ((const float*)&xg[3])[q];
            float ii = __builtin_amdgcn_rcpf(1.f + __expf(-vi));
            float ff = __builtin_amdgcn_rcpf(1.f + __expf(-vf));
            float gg = 1.f - 2.f * __builtin_amdgcn_rcpf(__expf(2.f*vg) + 1.f);
            float oo = 1.f / (1.f + __expf(-vo));
            float cn = fmaf(ff, c[q], ii * gg);
            c[q] = cn;
            float th = 1.f - 2.f * __builtin_amdgcn_rcpf(__expf(2.f*cn) + 1.f);
            float hh = oo * th;
            hm[q] = fmaxf(hm[q], hh);
            hval[q] = hh;
        }
        // repack h -> bf16 A-frag layout: kc = u>>5, sublane = ((u>>3)&3)*16 + row, j = u&7
        unsigned int p01 = f2bf(hval[0]) | (f2bf(hval[1]) << 16);
        unsigned int p23 = f2bf(hval[2]) | (f2bf(hval[3]) << 16);
        *(uint2*)&hpack[eu0 >> 5][((eu0 >> 3) & 3)*16 + w][eu0 & 7] = make_uint2(p01, p23);
        __syncthreads();
    }
    *(float4*)(feat + (size_t)(b0 + w)*LHID + eu0) = make_float4(hm[0], hm[1], hm[2], hm[3]);
}

// ---------------- final FC + sigmoid ----------------
__global__ __launch_bounds__(64) void final_k(
    const float* __restrict__ feat, const float* __restrict__ Wfc,
    const float* __restrict__ bfc, float* __restrict__ out)
{
    const int b = blockIdx.x * 64 + threadIdx.x;
    float s = bfc[0];
    for (int u = 0; u < LHID; u++)
        s = fmaf(feat[(size_t)b*LHID + u], Wfc[u], s);
    out[b] = 1.f / (1.f + __expf(-s));
}

extern "C" void kernel_launch(void* const* d_in, const int* in_sizes, int n_in,
                              void* d_out, int out_size, void* d_ws, size_t ws_size,
                              hipStream_t stream) {
    const float* kp  = (const float*)d_in[0];
    const float* W1  = (const float*)d_in[1];
    const float* b1  = (const float*)d_in[2];
    const float* W2  = (const float*)d_in[3];
    const float* b2  = (const float*)d_in[4];
    const float* Wih = (const float*)d_in[5];
    const float* Whh = (const float*)d_in[6];
    const float* bih = (const float*)d_in[7];
    const float* bhh = (const float*)d_in[8];
    const float* Wfc = (const float*)d_in[9];
    const float* bfc = (const float*)d_in[10];

    float* ws     = (float*)d_ws;
    float* Ahat   = ws + OFF_AHAT;
    float* WIT    = ws + OFF_WIT;
    float* bias   = ws + OFF_BIAS;
    unsigned short* Wpk = (unsigned short*)(ws + OFF_WPK);
    float* pooled = ws + OFF_POOLED;
    float* xw     = ws + OFF_XW;
    float* feat   = ws + OFF_FEAT;
    float* out    = (float*)d_out;

    hipLaunchKernelGGL(prep_ahat_k, dim3(1), dim3(64), 0, stream, Ahat);
    hipLaunchKernelGGL(prep_wt_k, dim3(128), dim3(256), 0, stream,
                       Wih, bih, bhh, WIT, bias);
    hipLaunchKernelGGL(prep_pack_k, dim3(128), dim3(256), 0, stream, Whh, Wpk);
    hipLaunchKernelGGL(gcn_pool_k, dim3(BB*TT), dim3(128), 0, stream,
                       kp, W1, b1, W2, b2, Ahat, pooled);
    hipLaunchKernelGGL(xw_gemm_k, dim3(BB*TT/16, 4), dim3(256), 0, stream,
                       pooled, WIT, bias, xw);
    hipLaunchKernelGGL(lstm_mfma_k, dim3(BB/8), dim3(512), 0, stream, xw, Wpk, feat);
    hipLaunchKernelGGL(final_k, dim3(4), dim3(64), 0, stream, feat, Wfc, bfc, out);
}